// Round 10
// baseline (635.974 us; speedup 1.0000x reference)
//
#include <hip/hip_runtime.h>

#define HH 96
#define WW 96
#define CC 21
#define BB 2
#define NN (HH*WW)          // 9216
#define NT16 (NN/16)        // 576 sorted 16-tiles per batch
#define NJB  (NN/32)        // 288 j-blocks per batch
#define NCONV (BB*CC)       // 42 conv planes (blocks 0..41)
#define NBILB (BB*NT16)     // 1152 bilateral tiles
#define NGRID 1024          // 4 blocks/CU x 256 CU -> ALL co-resident (no deadlock)
#define NBIL2 (NGRID - NCONV)   // 982 bilateral blocks; 170 handle a 2nd tile
#define PRUNE_T 20.0f       // exp2-domain skip threshold (mass <= N*2^-20)
#define GST 104             // LDS row stride for 96-wide bf16 rows

// feature pre-scale folds 1/2 and log2(e): k = exp2(-sum(diff^2))
#define KSA2 (0.84932184f / 160.0f)   // bilateral spatial
#define KSB2 (0.84932184f / 3.0f)     // bilateral color
#define GL2  (1.44269504f / 18.0f)    // spatial kernel exp(-d^2/18) in exp2 units

typedef __attribute__((ext_vector_type(4))) float f32x4;
typedef __attribute__((ext_vector_type(8))) short short8;
typedef __attribute__((ext_vector_type(4))) int int4v;

static __device__ inline unsigned pk_bf16(float a, float b) {
    unsigned ua = __builtin_bit_cast(unsigned, a);
    unsigned ub = __builtin_bit_cast(unsigned, b);
    ua += 0x7FFF + ((ua >> 16) & 1);
    ub += 0x7FFF + ((ub >> 16) & 1);
    return (ua >> 16) | (ub & 0xFFFF0000u);
}
static __device__ inline unsigned short bf16_1(float a) {
    unsigned ua = __builtin_bit_cast(unsigned, a);
    ua += 0x7FFF + ((ua >> 16) & 1);
    return (unsigned short)(ua >> 16);
}

// ===== D1: hist + tables + smht const rows (BOTH buffers) + BND + flags ====
__global__ __launch_bounds__(256) void histprep_kernel(
    const float* __restrict__ rgb, unsigned* __restrict__ gha,
    unsigned* __restrict__ ghb, float* __restrict__ sxt,
    unsigned short* __restrict__ gbt, unsigned short* __restrict__ smht0,
    unsigned short* __restrict__ smht1, unsigned* __restrict__ bnd,
    unsigned* __restrict__ cflag)
{
    int tid = threadIdx.x;
    int gid = blockIdx.x * 256 + tid;
    if (gid < BB * NN) {
        int b = gid / NN;
        const float* rp = rgb + (size_t)gid * 3;
        int cr = min(15, (int)rp[0] >> 4);
        int cg = min(15, (int)rp[1] >> 4);
        int cb = min(15, (int)rp[2] >> 4);
        int cell = b * 4096 + ((cr << 8) | (cg << 4) | cb);
        atomicAdd(&gha[cell], 1u);
        atomicAdd(&ghb[cell], 1u);
    }
    unsigned* s0 = (unsigned*)smht0;
    unsigned* s1 = (unsigned*)smht1;
    for (int o = gid; o < BB * 11 * (NN / 2); o += 104 * 256) {
        int b = o / (11 * (NN / 2));
        int rem = o - b * 11 * (NN / 2);
        int rr = rem / (NN / 2), col = rem - rr * (NN / 2);
        unsigned v = (rr == 0) ? 0x3F803F80u : 0u;
        size_t off = (size_t)(b * 32 + 21 + rr) * (NN / 2) + col;
        s0[off] = v; s1[off] = v;
    }
    if (gid < BB * NT16 * 3) {
        int t2 = gid / 3, f = gid - t2 * 3;
        bnd[t2 * 6 + 2 * f]     = 0x7F7FFFFFu;   // lo = +FLT_MAX bits (poison-proof)
        bnd[t2 * 6 + 2 * f + 1] = 0u;            // hi = 0 (features >= 0)
    }
    if (gid < 16) cflag[gid] = 0u;               // conv flags (it*2 + b)
    if (blockIdx.x == 0) {
        __shared__ float gt[96];
        if (tid < 96) gt[tid] = __builtin_amdgcn_exp2f(-(float)(tid * tid) * GL2);
        __syncthreads();
        if (tid < 96) {
            float s = 0.f;
            for (int v = 0; v < 96; v++) s += gt[abs(tid - v)];
            sxt[tid] = s;
            for (int v = 0; v < 96; v++) gbt[tid * 96 + v] = bf16_1(gt[abs(tid - v)]);
        }
    }
}

// ===== D2: scan + scatter + bbox + sinv + feature norm + iter-0 softmax ====
__global__ __launch_bounds__(256) void scanscatter_kernel(
    const float* __restrict__ rgb, const unsigned* __restrict__ gha,
    unsigned* __restrict__ ghb, const unsigned* __restrict__ sent,
    int* __restrict__ sinv, float* __restrict__ fjs, unsigned* __restrict__ bnd,
    const float* __restrict__ q, unsigned short* __restrict__ smpb,
    unsigned short* __restrict__ smht)
{
    __shared__ int sOff[4096];
    __shared__ int ps[256];
    unsigned sv = sent[0];
    int t = threadIdx.x;
    int blk = blockIdx.x;
    int b = blk / (36);                       // 36 blocks per batch
    int base = b * 4096 + t * 16;
    int loc[16], s = 0;
#pragma unroll
    for (int k = 0; k < 16; k++) { loc[k] = (int)(gha[base + k] - sv); s += loc[k]; }
    ps[t] = s;
    __syncthreads();
    for (int off = 1; off < 256; off <<= 1) {
        int add = (t >= off) ? ps[t - off] : 0;
        __syncthreads();
        ps[t] += add;
        __syncthreads();
    }
    int run = ps[t] - s;
#pragma unroll
    for (int k = 0; k < 16; k++) { sOff[t * 16 + k] = run; run += loc[k]; }
    __syncthreads();
    int idx = blk * 256 + t;                  // global pixel, == b*NN + p
    int p = idx - b * NN;
    const float* rp = rgb + (size_t)idx * 3;
    float r = rp[0], g = rp[1], bl = rp[2];
    int cr = min(15, (int)r >> 4);
    int cg = min(15, (int)g >> 4);
    int cb = min(15, (int)bl >> 4);
    int cell = (cr << 8) | (cg << 4) | cb;
    unsigned old = atomicSub(&ghb[b * 4096 + cell], 1u);
    int pos = sOff[cell] + (int)(old - sv) - 1;
    sinv[b * NN + pos] = p;                   // inverse permutation (sorted -> pixel)
    int y = p / WW, x = p - y * WW;
    float fr = r * KSB2, fg = g * KSB2, fb2 = bl * KSB2;
    float ys = (float)y * KSA2, xs = (float)x * KSA2;
    float* fb = fjs + (size_t)b * 6 * NN;
    fb[0 * NN + pos] = fr;
    fb[1 * NN + pos] = fg;
    fb[2 * NN + pos] = fb2;
    fb[3 * NN + pos] = ys;
    fb[4 * NN + pos] = xs;
    fb[5 * NN + pos] = fr*fr + fg*fg + fb2*fb2 + ys*ys + xs*xs;  // ||fj||^2
    unsigned* bq = bnd + (size_t)(b * NT16 + (pos >> 4)) * 6;
    atomicMin(&bq[0], __float_as_uint(fr));  atomicMax(&bq[1], __float_as_uint(fr));
    atomicMin(&bq[2], __float_as_uint(fg));  atomicMax(&bq[3], __float_as_uint(fg));
    atomicMin(&bq[4], __float_as_uint(fb2)); atomicMax(&bq[5], __float_as_uint(fb2));
    const float* qp = q + (size_t)idx * CC;
    float v[CC], mx = -1e30f;
#pragma unroll
    for (int c = 0; c < CC; c++) { v[c] = qp[c]; mx = fmaxf(mx, v[c]); }
    float ssum = 0.f;
#pragma unroll
    for (int c = 0; c < CC; c++) { v[c] = __expf(v[c] - mx); ssum += v[c]; }
    float inv = 1.0f / ssum;
#pragma unroll
    for (int c = 0; c < CC; c++) {
        unsigned short h = bf16_1(v[c] * inv);
        smpb[(size_t)(b * CC + c) * NN + p] = h;
        smht[(size_t)(b * 32 + c) * NN + pos] = h;
    }
}

// ---------------- bilateral helpers (dot-product form, depth-2 pipeline) ----
struct JSet { float vf[6][8]; short8 sb0, sb1; };

static __device__ __forceinline__ void load_jset(
    JSet& s, const float* __restrict__ fb, const unsigned short* __restrict__ smb,
    int jb, int quad, int l16)
{
    int coff = jb * 32 + quad * 8;
#pragma unroll
    for (int f = 0; f < 6; f++) {
        const float4* pf = (const float4*)(fb + (size_t)f * NN + coff);
        float4 lo = pf[0], hi = pf[1];
        s.vf[f][0] = lo.x; s.vf[f][1] = lo.y; s.vf[f][2] = lo.z; s.vf[f][3] = lo.w;
        s.vf[f][4] = hi.x; s.vf[f][5] = hi.y; s.vf[f][6] = hi.z; s.vf[f][7] = hi.w;
    }
    s.sb0 = *(const short8*)(smb + (size_t)l16 * NN + coff);
    s.sb1 = *(const short8*)(smb + (size_t)(16 + l16) * NN + coff);
}

// kf = exp2(-(ci + nj - 2*fi.fj)) = exp2(ai - nj + sum gk*vjk); ai=-||fi||^2, gk=2fik
static __device__ __forceinline__ void compute_jset(
    const JSet& s, float g0, float g1, float g2, float g3, float g4, float ai,
    f32x4& acc0, f32x4& acc1)
{
    float kf[8];
#pragma unroll
    for (int e = 0; e < 8; e++) {
        float sm = ai - s.vf[5][e];
        sm = fmaf(g0, s.vf[0][e], sm);
        sm = fmaf(g1, s.vf[1][e], sm);
        sm = fmaf(g2, s.vf[2][e], sm);
        sm = fmaf(g3, s.vf[3][e], sm);
        sm = fmaf(g4, s.vf[4][e], sm);
        kf[e] = __builtin_amdgcn_exp2f(sm);
    }
    int4v ap = { (int)pk_bf16(kf[0], kf[1]), (int)pk_bf16(kf[2], kf[3]),
                 (int)pk_bf16(kf[4], kf[5]), (int)pk_bf16(kf[6], kf[7]) };
    short8 afrag = __builtin_bit_cast(short8, ap);
    acc0 = __builtin_amdgcn_mfma_f32_16x16x32_bf16(afrag, s.sb0, acc0, 0, 0, 0);
    acc1 = __builtin_amdgcn_mfma_f32_16x16x32_bf16(afrag, s.sb1, acc1, 0, 0, 0);
}

// ===== K2: one kernel per CRF iteration (R8 geometry + R5 fused update) ====
// 1024 blocks x 512 thr, launch_bounds(512,8): 4 blocks/CU -> ALL co-resident
// -> the flag wait cannot deadlock. Blocks 0..41: conv plane -> RELEASE flag
// -> exit. Blocks 42..1023: one tile (170 blocks take a 2nd): mask ->
// 8-wave bilateral -> LDS combine -> flag-wait + ACQUIRE (placed AFTER all
// heavy reads; only ~2.6KB of spf/u read post-invalidate, unlike R5's
// poisoned tt-loop) -> R5-validated LDS update+softmax tail. SMHT is
// double-buffered across iterations (read parity it, write parity it+1).
__global__ __launch_bounds__(512, 8) void crf_iter_kernel(
    unsigned short* smpb, const unsigned short* __restrict__ gbt,
    const float* __restrict__ sxt, float* __restrict__ spf,
    const unsigned short* __restrict__ smht_r, unsigned short* __restrict__ smht_w,
    const float* __restrict__ fjs, const unsigned* __restrict__ bnd,
    const int* __restrict__ sinv, const float* __restrict__ u,
    const float* __restrict__ Ws, const float* __restrict__ Wb,
    const float* __restrict__ Mmat, float* __restrict__ qout,
    unsigned* cflag, int it, int wr)
{
    __shared__ __align__(16) char sh[19968];
    int tid = threadIdx.x;
    int lane = tid & 63, w = tid >> 6;         // w in 0..7
    int quad = lane >> 4, l16 = lane & 15;
    int bid = blockIdx.x;

    if (bid < NCONV) {
        // ---- conv role: plane (b,c) = bid ----
        unsigned short* C1t = (unsigned short*)sh;
        const unsigned short* plane = smpb + (size_t)bid * NN;
        for (int mt = w; mt < 6; mt += 8) {
            int m0 = mt * 16;
            short8 a[3];
#pragma unroll
            for (int kk = 0; kk < 3; kk++)
                a[kk] = *(const short8*)(plane + (size_t)(m0 + l16) * 96 + kk * 32 + quad * 8);
            f32x4 acc[6];
#pragma unroll
            for (int nt = 0; nt < 6; nt++) acc[nt] = (f32x4){0.f, 0.f, 0.f, 0.f};
#pragma unroll
            for (int nt = 0; nt < 6; nt++) {
#pragma unroll
                for (int kk = 0; kk < 3; kk++) {
                    short8 bf = *(const short8*)(gbt + (nt * 16 + l16) * 96 + kk * 32 + quad * 8);
                    acc[nt] = __builtin_amdgcn_mfma_f32_16x16x32_bf16(a[kk], bf, acc[nt], 0, 0, 0);
                }
            }
#pragma unroll
            for (int nt = 0; nt < 6; nt++) {
                unsigned* dst = (unsigned*)&C1t[(nt * 16 + l16) * GST + m0 + quad * 4];
                dst[0] = pk_bf16(acc[nt][0], acc[nt][1]);
                dst[1] = pk_bf16(acc[nt][2], acc[nt][3]);
            }
        }
        __syncthreads();
        float* outp = spf + (size_t)bid * NN;
        for (int mt = w; mt < 6; mt += 8) {
            int m0 = mt * 16;
            short8 a[3];
#pragma unroll
            for (int kk = 0; kk < 3; kk++)
                a[kk] = *(const short8*)(gbt + (m0 + l16) * 96 + kk * 32 + quad * 8);
            f32x4 acc[6];
#pragma unroll
            for (int nt = 0; nt < 6; nt++) acc[nt] = (f32x4){0.f, 0.f, 0.f, 0.f};
#pragma unroll
            for (int nt = 0; nt < 6; nt++) {
#pragma unroll
                for (int kk = 0; kk < 3; kk++) {
                    short8 bf = *(const short8*)&C1t[(nt * 16 + l16) * GST + kk * 32 + quad * 8];
                    acc[nt] = __builtin_amdgcn_mfma_f32_16x16x32_bf16(a[kk], bf, acc[nt], 0, 0, 0);
                }
            }
#pragma unroll
            for (int nt = 0; nt < 6; nt++) {
                int x = nt * 16 + l16;
                float sx = sxt[x];
#pragma unroll
                for (int r = 0; r < 4; r++) {
                    int y = m0 + quad * 4 + r;
                    float invn = __builtin_amdgcn_rcpf(sxt[y] * sx);
                    outp[y * 96 + x] = acc[nt][r] * invn;
                }
            }
        }
        __syncthreads();   // drains stores (compiler emits vmcnt(0) before barrier)
        if (tid == 0)
            __hip_atomic_fetch_add(&cflag[it * 2 + bid / CC], 1u,
                                   __ATOMIC_RELEASE, __HIP_MEMORY_SCOPE_AGENT);
        return;
    }

    // ---- bilateral + fused update: LDS layout ----
    unsigned short* jl = (unsigned short*)sh;          // [0,640)
    float* cbuf  = (float*)(sh + 640);                 // 8*384 floats = 12288 B
    float* sW    = (float*)(sh + 12928);               // 3*441 floats = 5292 B
    int*   sinvp = (int*)(sh + 18220);                 // 16
    float* ninvb = (float*)(sh + 18284);               // 16
    // tail overlays (valid only after all cbuf reads complete):
    float* blvb  = (float*)(sh + 640);                 // 336
    float* spvb  = (float*)(sh + 1984);                // 336
    float* msgb  = (float*)(sh + 3328);                // 336
    float* qvb   = (float*)(sh + 4672);                // 336

    for (int t2 = tid; t2 < 441; t2 += 512) {
        sW[t2] = Ws[t2]; sW[441 + t2] = Wb[t2]; sW[882 + t2] = Mmat[t2];
    }

    for (int tt = 0; tt < 2; ++tt) {
        int bt = (bid - NCONV) + tt * NBIL2;    // uniform per block
        if (bt >= NBILB) break;
        int b = bt / NT16, tile16 = bt - b * NT16;
        __syncthreads();                        // sW staged / LDS reuse across tt

        // mask: keep-list (8 waves redundant, identical values)
        const float* bndf = (const float*)bnd;
        const float* tb = bndf + (size_t)bt * 6;
        float tlo0 = tb[0], thi0 = tb[1], tlo1 = tb[2], thi1 = tb[3], tlo2 = tb[4], thi2 = tb[5];
        const float* bb = bndf + (size_t)b * NT16 * 6;
        int n = 0;
#pragma unroll
        for (int r = 0; r < 5; r++) {
            int jb = r * 64 + lane;
            bool keep = false;
            if (jb < NJB) {
                const float* a0 = bb + (size_t)(2 * jb) * 6;
                float s = 0.f;
#pragma unroll
                for (int f = 0; f < 3; f++) {
                    float jlo = fminf(a0[2 * f], a0[6 + 2 * f]);
                    float jhi = fmaxf(a0[2 * f + 1], a0[6 + 2 * f + 1]);
                    float lo = (f == 0) ? tlo0 : (f == 1) ? tlo1 : tlo2;
                    float hi = (f == 0) ? thi0 : (f == 1) ? thi1 : thi2;
                    float gap = fmaxf(0.f, fmaxf(lo - jhi, jlo - hi));
                    s = fmaf(gap, gap, s);
                }
                keep = (s <= PRUNE_T);
            }
            unsigned long long m = __ballot(keep);
            if (keep) {
                int pre = __popcll(m & ((1ull << lane) - 1ull));
                jl[n + pre] = (unsigned short)jb;
            }
            n += __popcll(m);
        }
        __syncthreads();

        // bilateral: 8 waves split keep-list stride-8 (dot-product form)
        int i = tile16 * 16 + l16;
        const float* fb = fjs + (size_t)b * 6 * NN;
        float fi0 = fb[0 * NN + i], fi1 = fb[1 * NN + i], fi2 = fb[2 * NN + i];
        float fi3 = fb[3 * NN + i], fi4 = fb[4 * NN + i];
        float ai = -(fi0*fi0 + fi1*fi1 + fi2*fi2 + fi3*fi3 + fi4*fi4);
        float g0 = 2.f*fi0, g1 = 2.f*fi1, g2 = 2.f*fi2, g3 = 2.f*fi3, g4 = 2.f*fi4;
        f32x4 acc0 = {0.f, 0.f, 0.f, 0.f};
        f32x4 acc1 = {0.f, 0.f, 0.f, 0.f};
        const unsigned short* smb = smht_r + (size_t)b * 32 * NN;
        int k = w;
        if (k < n) {
            JSet A, B;
            load_jset(A, fb, smb, jl[k], quad, l16);
            while (true) {
                int kn = k + 8;
                load_jset(B, fb, smb, jl[kn < n ? kn : k], quad, l16);
                compute_jset(A, g0, g1, g2, g3, g4, ai, acc0, acc1);
                k = kn;
                if (k >= n) break;
                kn = k + 8;
                load_jset(A, fb, smb, jl[kn < n ? kn : k], quad, l16);
                compute_jset(B, g0, g1, g2, g3, g4, ai, acc0, acc1);
                k = kn;
                if (k >= n) break;
            }
        }
#pragma unroll
        for (int r = 0; r < 4; r++)
            cbuf[w * 384 + (quad * 4 + r) * 24 + l16] = acc0[r];
        if (l16 < 6) {
#pragma unroll
            for (int r = 0; r < 4; r++)
                cbuf[w * 384 + (quad * 4 + r) * 24 + 16 + l16] = acc1[r];
        }
        __syncthreads();

        // pre-wait prep (reads cbuf only) + flag wait (acquire AFTER heavy reads)
        if (tid < 16) {
            sinvp[tid] = sinv[b * NN + tile16 * 16 + tid];
            float s4 = 0.f;
#pragma unroll
            for (int ww = 0; ww < 8; ww++) s4 += cbuf[ww * 384 + tid * 24 + 21];
            ninvb[tid] = 1.0f / s4;
        }
        if (tid == 0) {
            while (__hip_atomic_load(&cflag[it * 2 + b], __ATOMIC_RELAXED,
                                     __HIP_MEMORY_SCOPE_AGENT) < (unsigned)CC)
                __builtin_amdgcn_s_sleep(2);
            (void)__hip_atomic_load(&cflag[it * 2 + b], __ATOMIC_ACQUIRE,
                                    __HIP_MEMORY_SCOPE_AGENT);
        }
        __syncthreads();

        // blv/spv in registers (cbuf still intact), then overlay into LDS
        int rr = 0, cc2 = 0, pp = 0;
        float blv_r = 0.f, spv_r = 0.f;
        if (tid < 16 * CC) {
            rr = tid / CC; cc2 = tid - rr * CC;
            float s4 = 0.f;
#pragma unroll
            for (int ww = 0; ww < 8; ww++) s4 += cbuf[ww * 384 + rr * 24 + cc2];
            blv_r = s4 * ninvb[rr];
            pp = sinvp[rr];
            spv_r = spf[(size_t)(b * CC + cc2) * NN + pp];
        }
        __syncthreads();                        // all cbuf reads complete
        if (tid < 16 * CC) { blvb[tid] = blv_r; spvb[tid] = spv_r; }
        __syncthreads();
        float msg_r = 0.f;
        if (tid < 16 * CC) {
            const float* wr2 = &sW[cc2 * CC];
            const float* br = &sW[441 + cc2 * CC];
#pragma unroll
            for (int c2 = 0; c2 < CC; c2++) msg_r = fmaf(wr2[c2], spvb[rr * CC + c2], msg_r);
#pragma unroll
            for (int c2 = 0; c2 < CC; c2++) msg_r = fmaf(br[c2], blvb[rr * CC + c2], msg_r);
        }
        __syncthreads();
        if (tid < 16 * CC) msgb[tid] = msg_r;
        __syncthreads();
        if (tid < 16 * CC) {
            float a = u[((size_t)b * NN + pp) * CC + cc2];
            const float* mr = &sW[882 + cc2 * CC];
#pragma unroll
            for (int c2 = 0; c2 < CC; c2++) a = fmaf(-mr[c2], msgb[rr * CC + c2], a);
            if (wr) qvb[tid] = a;
            else qout[((size_t)b * NN + pp) * CC + cc2] = a;
        }
        if (wr) {
            __syncthreads();
            if (tid < 16) {
                int r = tid;
                float m = -1e30f;
#pragma unroll
                for (int c = 0; c < CC; c++) m = fmaxf(m, qvb[r * CC + c]);
                float ssum = 0.f;
                float ev[CC];
#pragma unroll
                for (int c = 0; c < CC; c++) { ev[c] = __expf(qvb[r * CC + c] - m); ssum += ev[c]; }
                float inv = 1.0f / ssum;
                int p = sinvp[r];
                int s = tile16 * 16 + r;
#pragma unroll
                for (int c = 0; c < CC; c++) {
                    unsigned short h = bf16_1(ev[c] * inv);
                    smpb[(size_t)(b * CC + c) * NN + p] = h;
                    smht_w[(size_t)(b * 32 + c) * NN + s] = h;
                }
            }
        }
    }
}

extern "C" void kernel_launch(void* const* d_in, const int* in_sizes, int n_in,
                              void* d_out, int out_size, void* d_ws, size_t ws_size,
                              hipStream_t stream)
{
    const float* unary = (const float*)d_in[0];  // [B,H,W,C]
    const float* rgb   = (const float*)d_in[1];  // [B,H,W,3]
    const float* Ws    = (const float*)d_in[2];
    const float* Wb    = (const float*)d_in[3];
    const float* M     = (const float*)d_in[4];
    float* out = (float*)d_out;                  // [B,N,C]

    float* SXT  = (float*)d_ws;                            // 96
    float* FJS  = SXT + 96;                                // B*6*N (5 feats + norm)
    float* SPF  = FJS + (size_t)BB * 6 * NN;               // B*21*N
    unsigned* BND = (unsigned*)(SPF + (size_t)BB * CC * NN);   // B*576*6
    unsigned* GHA = BND + (size_t)BB * NT16 * 6;           // B*4096 (poison-based)
    unsigned* GHB = GHA + BB * 4096;                       // B*4096 (poison-based)
    unsigned* CFLAG = GHB + BB * 4096;                     // 16 (zeroed in D1)
    unsigned* SENT = CFLAG + 16;                           // 1 (NEVER written)
    int*   SINV = (int*)(SENT + 1);                        // B*N
    unsigned short* SMHT0 = (unsigned short*)(SINV + BB * NN); // B*32*N
    unsigned short* SMHT1 = SMHT0 + (size_t)BB * 32 * NN;  // B*32*N
    unsigned short* SMPB  = SMHT1 + (size_t)BB * 32 * NN;  // B*21*N
    unsigned short* GBT   = SMPB + (size_t)BB * CC * NN;   // 96*96

    histprep_kernel<<<104, 256, 0, stream>>>(rgb, GHA, GHB, SXT, GBT, SMHT0, SMHT1,
                                             BND, CFLAG);
    scanscatter_kernel<<<BB * 36, 256, 0, stream>>>(rgb, GHA, GHB, SENT, SINV,
                                                    FJS, BND, unary, SMPB, SMHT0);
    for (int it = 0; it < 5; ++it) {
        unsigned short* SR = (it & 1) ? SMHT1 : SMHT0;
        unsigned short* SW = (it & 1) ? SMHT0 : SMHT1;
        crf_iter_kernel<<<NGRID, 512, 0, stream>>>(
            SMPB, GBT, SXT, SPF, SR, SW, FJS, BND, SINV, unary,
            Ws, Wb, M, out, CFLAG, it, (it < 4) ? 1 : 0);
    }
}

// Round 11
// 481.990 us; speedup vs baseline: 1.3195x; 1.3195x over previous
//
#include <hip/hip_runtime.h>

#define HH 96
#define WW 96
#define CC 21
#define BB 2
#define NN (HH*WW)          // 9216
#define NT16 (NN/16)        // 576 sorted 16-tiles per batch
#define NJB  (NN/32)        // 288 j-blocks per batch
#define NCONV (BB*CC)       // 42 conv planes (tickets 0..41)
#define NBILB (BB*NT16)     // 1152 bilateral tiles (tickets 42..1193)
#define NTOT (NCONV + NBILB)
#define NGRID 512           // 2 blocks/CU at natural VGPR -> all co-resident
#define PRUNE_T 20.0f       // exp2-domain skip threshold (mass <= N*2^-20)
#define GST 104             // LDS row stride for 96-wide bf16 rows

// feature pre-scale folds 1/2 and log2(e): k = exp2(-sum(diff^2))
#define KSA2 (0.84932184f / 160.0f)   // bilateral spatial
#define KSB2 (0.84932184f / 3.0f)     // bilateral color
#define GL2  (1.44269504f / 18.0f)    // spatial kernel exp(-d^2/18) in exp2 units

typedef __attribute__((ext_vector_type(4))) float f32x4;
typedef __attribute__((ext_vector_type(8))) short short8;
typedef __attribute__((ext_vector_type(4))) int int4v;

static __device__ inline unsigned pk_bf16(float a, float b) {
    unsigned ua = __builtin_bit_cast(unsigned, a);
    unsigned ub = __builtin_bit_cast(unsigned, b);
    ua += 0x7FFF + ((ua >> 16) & 1);
    ub += 0x7FFF + ((ub >> 16) & 1);
    return (ua >> 16) | (ub & 0xFFFF0000u);
}
static __device__ inline unsigned short bf16_1(float a) {
    unsigned ua = __builtin_bit_cast(unsigned, a);
    ua += 0x7FFF + ((ua >> 16) & 1);
    return (unsigned short)(ua >> 16);
}

// ===== D1: hist + tables + smht const rows (BOTH buffers) + BND + flags/tk =
__global__ __launch_bounds__(256) void histprep_kernel(
    const float* __restrict__ rgb, unsigned* __restrict__ gha,
    unsigned* __restrict__ ghb, float* __restrict__ sxt,
    unsigned short* __restrict__ gbt, unsigned short* __restrict__ smht0,
    unsigned short* __restrict__ smht1, unsigned* __restrict__ bnd,
    unsigned* __restrict__ cflag)
{
    int tid = threadIdx.x;
    int gid = blockIdx.x * 256 + tid;
    if (gid < BB * NN) {
        int b = gid / NN;
        const float* rp = rgb + (size_t)gid * 3;
        int cr = min(15, (int)rp[0] >> 4);
        int cg = min(15, (int)rp[1] >> 4);
        int cb = min(15, (int)rp[2] >> 4);
        int cell = b * 4096 + ((cr << 8) | (cg << 4) | cb);
        atomicAdd(&gha[cell], 1u);
        atomicAdd(&ghb[cell], 1u);
    }
    unsigned* s0 = (unsigned*)smht0;
    unsigned* s1 = (unsigned*)smht1;
    for (int o = gid; o < BB * 11 * (NN / 2); o += 104 * 256) {
        int b = o / (11 * (NN / 2));
        int rem = o - b * 11 * (NN / 2);
        int rr = rem / (NN / 2), col = rem - rr * (NN / 2);
        unsigned v = (rr == 0) ? 0x3F803F80u : 0u;
        size_t off = (size_t)(b * 32 + 21 + rr) * (NN / 2) + col;
        s0[off] = v; s1[off] = v;
    }
    if (gid < BB * NT16 * 3) {
        int t2 = gid / 3, f = gid - t2 * 3;
        bnd[t2 * 6 + 2 * f]     = 0x7F7FFFFFu;   // lo = +FLT_MAX bits (poison-proof)
        bnd[t2 * 6 + 2 * f + 1] = 0u;            // hi = 0 (features >= 0)
    }
    if (gid < 24) cflag[gid] = 0u;   // [0..9] conv flags (it*2+b), [16..20] tickets
    if (blockIdx.x == 0) {
        __shared__ float gt[96];
        if (tid < 96) gt[tid] = __builtin_amdgcn_exp2f(-(float)(tid * tid) * GL2);
        __syncthreads();
        if (tid < 96) {
            float s = 0.f;
            for (int v = 0; v < 96; v++) s += gt[abs(tid - v)];
            sxt[tid] = s;
            for (int v = 0; v < 96; v++) gbt[tid * 96 + v] = bf16_1(gt[abs(tid - v)]);
        }
    }
}

// ===== D2: scan + scatter + bbox + sinv + feature norm + iter-0 softmax ====
__global__ __launch_bounds__(256) void scanscatter_kernel(
    const float* __restrict__ rgb, const unsigned* __restrict__ gha,
    unsigned* __restrict__ ghb, const unsigned* __restrict__ sent,
    int* __restrict__ sinv, float* __restrict__ fjs, unsigned* __restrict__ bnd,
    const float* __restrict__ q, unsigned short* __restrict__ smpb,
    unsigned short* __restrict__ smht)
{
    __shared__ int sOff[4096];
    __shared__ int ps[256];
    unsigned sv = sent[0];
    int t = threadIdx.x;
    int blk = blockIdx.x;
    int b = blk / (36);                       // 36 blocks per batch
    int base = b * 4096 + t * 16;
    int loc[16], s = 0;
#pragma unroll
    for (int k = 0; k < 16; k++) { loc[k] = (int)(gha[base + k] - sv); s += loc[k]; }
    ps[t] = s;
    __syncthreads();
    for (int off = 1; off < 256; off <<= 1) {
        int add = (t >= off) ? ps[t - off] : 0;
        __syncthreads();
        ps[t] += add;
        __syncthreads();
    }
    int run = ps[t] - s;
#pragma unroll
    for (int k = 0; k < 16; k++) { sOff[t * 16 + k] = run; run += loc[k]; }
    __syncthreads();
    int idx = blk * 256 + t;                  // global pixel, == b*NN + p
    int p = idx - b * NN;
    const float* rp = rgb + (size_t)idx * 3;
    float r = rp[0], g = rp[1], bl = rp[2];
    int cr = min(15, (int)r >> 4);
    int cg = min(15, (int)g >> 4);
    int cb = min(15, (int)bl >> 4);
    int cell = (cr << 8) | (cg << 4) | cb;
    unsigned old = atomicSub(&ghb[b * 4096 + cell], 1u);
    int pos = sOff[cell] + (int)(old - sv) - 1;
    sinv[b * NN + pos] = p;                   // inverse permutation (sorted -> pixel)
    int y = p / WW, x = p - y * WW;
    float fr = r * KSB2, fg = g * KSB2, fb2 = bl * KSB2;
    float ys = (float)y * KSA2, xs = (float)x * KSA2;
    float* fb = fjs + (size_t)b * 6 * NN;
    fb[0 * NN + pos] = fr;
    fb[1 * NN + pos] = fg;
    fb[2 * NN + pos] = fb2;
    fb[3 * NN + pos] = ys;
    fb[4 * NN + pos] = xs;
    fb[5 * NN + pos] = fr*fr + fg*fg + fb2*fb2 + ys*ys + xs*xs;  // ||fj||^2
    unsigned* bq = bnd + (size_t)(b * NT16 + (pos >> 4)) * 6;
    atomicMin(&bq[0], __float_as_uint(fr));  atomicMax(&bq[1], __float_as_uint(fr));
    atomicMin(&bq[2], __float_as_uint(fg));  atomicMax(&bq[3], __float_as_uint(fg));
    atomicMin(&bq[4], __float_as_uint(fb2)); atomicMax(&bq[5], __float_as_uint(fb2));
    const float* qp = q + (size_t)idx * CC;
    float v[CC], mx = -1e30f;
#pragma unroll
    for (int c = 0; c < CC; c++) { v[c] = qp[c]; mx = fmaxf(mx, v[c]); }
    float ssum = 0.f;
#pragma unroll
    for (int c = 0; c < CC; c++) { v[c] = __expf(v[c] - mx); ssum += v[c]; }
    float inv = 1.0f / ssum;
#pragma unroll
    for (int c = 0; c < CC; c++) {
        unsigned short h = bf16_1(v[c] * inv);
        smpb[(size_t)(b * CC + c) * NN + p] = h;
        smht[(size_t)(b * 32 + c) * NN + pos] = h;
    }
}

// ---------------- bilateral helpers (dot-product form, depth-2 pipeline) ----
struct JSet { float vf[6][8]; short8 sb0, sb1; };

static __device__ __forceinline__ void load_jset(
    JSet& s, const float* __restrict__ fb, const unsigned short* __restrict__ smb,
    int jb, int quad, int l16)
{
    int coff = jb * 32 + quad * 8;
#pragma unroll
    for (int f = 0; f < 6; f++) {
        const float4* pf = (const float4*)(fb + (size_t)f * NN + coff);
        float4 lo = pf[0], hi = pf[1];
        s.vf[f][0] = lo.x; s.vf[f][1] = lo.y; s.vf[f][2] = lo.z; s.vf[f][3] = lo.w;
        s.vf[f][4] = hi.x; s.vf[f][5] = hi.y; s.vf[f][6] = hi.z; s.vf[f][7] = hi.w;
    }
    s.sb0 = *(const short8*)(smb + (size_t)l16 * NN + coff);
    s.sb1 = *(const short8*)(smb + (size_t)(16 + l16) * NN + coff);
}

// kf = exp2(-(ci + nj - 2*fi.fj)) = exp2(ai - nj + sum gk*vjk); ai=-||fi||^2, gk=2fik
static __device__ __forceinline__ void compute_jset(
    const JSet& s, float g0, float g1, float g2, float g3, float g4, float ai,
    f32x4& acc0, f32x4& acc1)
{
    float kf[8];
#pragma unroll
    for (int e = 0; e < 8; e++) {
        float sm = ai - s.vf[5][e];
        sm = fmaf(g0, s.vf[0][e], sm);
        sm = fmaf(g1, s.vf[1][e], sm);
        sm = fmaf(g2, s.vf[2][e], sm);
        sm = fmaf(g3, s.vf[3][e], sm);
        sm = fmaf(g4, s.vf[4][e], sm);
        kf[e] = __builtin_amdgcn_exp2f(sm);
    }
    int4v ap = { (int)pk_bf16(kf[0], kf[1]), (int)pk_bf16(kf[2], kf[3]),
                 (int)pk_bf16(kf[4], kf[5]), (int)pk_bf16(kf[6], kf[7]) };
    short8 afrag = __builtin_bit_cast(short8, ap);
    acc0 = __builtin_amdgcn_mfma_f32_16x16x32_bf16(afrag, s.sb0, acc0, 0, 0, 0);
    acc1 = __builtin_amdgcn_mfma_f32_16x16x32_bf16(afrag, s.sb1, acc1, 0, 0, 0);
}

// ===== K2: one kernel per CRF iteration — ticket pool, NO forced occupancy =
// R10 failed because launch_bounds(512,8) forced VGPR=32 -> 213MB scratch
// spill (counter-proven). This retry: natural VGPR (~90-128, 2 blocks/CU),
// 512 blocks = exactly resident capacity, and a TICKET POOL for roles:
// tickets 0..41 = conv planes, 42.. = tiles. Only resident blocks grab
// tickets, so producers always run before any consumer spins -> deadlock
// impossible regardless of dispatch order. Acquire placed AFTER all heavy
// bilateral reads (only ~2.6KB spf/u read post-invalidate). SMHT double-
// buffered across iterations.
__global__ __launch_bounds__(512) void crf_iter_kernel(
    unsigned short* smpb, const unsigned short* __restrict__ gbt,
    const float* __restrict__ sxt, float* __restrict__ spf,
    const unsigned short* __restrict__ smht_r, unsigned short* __restrict__ smht_w,
    const float* __restrict__ fjs, const unsigned* __restrict__ bnd,
    const int* __restrict__ sinv, const float* __restrict__ u,
    const float* __restrict__ Ws, const float* __restrict__ Wb,
    const float* __restrict__ Mmat, float* __restrict__ qout,
    unsigned* cflag, unsigned* tk, int it, int wr)
{
    __shared__ __align__(16) char sh[19968];
    __shared__ int curT;
    int tid = threadIdx.x;
    int lane = tid & 63, w = tid >> 6;         // w in 0..7
    int quad = lane >> 4, l16 = lane & 15;

    // LDS layout (tile role):
    unsigned short* jl = (unsigned short*)sh;          // [0,640)
    float* cbuf  = (float*)(sh + 640);                 // 8*384 floats = 12288 B
    float* sW    = (float*)(sh + 12928);               // 3*441 floats = 5292 B
    int*   sinvp = (int*)(sh + 18220);                 // 16
    float* ninvb = (float*)(sh + 18284);               // 16
    // tail overlays (valid only after all cbuf reads complete):
    float* blvb  = (float*)(sh + 640);                 // 336
    float* spvb  = (float*)(sh + 1984);                // 336
    float* msgb  = (float*)(sh + 3328);                // 336
    float* qvb   = (float*)(sh + 4672);                // 336

    bool swLoaded = false;                     // uniform per block

    while (true) {
        __syncthreads();                       // LDS + curT reuse protection
        if (tid == 0) curT = (int)__hip_atomic_fetch_add(&tk[it], 1u,
                                 __ATOMIC_RELAXED, __HIP_MEMORY_SCOPE_AGENT);
        __syncthreads();
        int t = curT;
        if (t >= NTOT) break;

        if (t < NCONV) {
            // ---- conv role: plane (b,c) = t ----
            unsigned short* C1t = (unsigned short*)sh;
            const unsigned short* plane = smpb + (size_t)t * NN;
            for (int mt = w; mt < 6; mt += 8) {
                int m0 = mt * 16;
                short8 a[3];
#pragma unroll
                for (int kk = 0; kk < 3; kk++)
                    a[kk] = *(const short8*)(plane + (size_t)(m0 + l16) * 96 + kk * 32 + quad * 8);
                f32x4 acc[6];
#pragma unroll
                for (int nt = 0; nt < 6; nt++) acc[nt] = (f32x4){0.f, 0.f, 0.f, 0.f};
#pragma unroll
                for (int nt = 0; nt < 6; nt++) {
#pragma unroll
                    for (int kk = 0; kk < 3; kk++) {
                        short8 bf = *(const short8*)(gbt + (nt * 16 + l16) * 96 + kk * 32 + quad * 8);
                        acc[nt] = __builtin_amdgcn_mfma_f32_16x16x32_bf16(a[kk], bf, acc[nt], 0, 0, 0);
                    }
                }
#pragma unroll
                for (int nt = 0; nt < 6; nt++) {
                    unsigned* dst = (unsigned*)&C1t[(nt * 16 + l16) * GST + m0 + quad * 4];
                    dst[0] = pk_bf16(acc[nt][0], acc[nt][1]);
                    dst[1] = pk_bf16(acc[nt][2], acc[nt][3]);
                }
            }
            __syncthreads();
            float* outp = spf + (size_t)t * NN;
            for (int mt = w; mt < 6; mt += 8) {
                int m0 = mt * 16;
                short8 a[3];
#pragma unroll
                for (int kk = 0; kk < 3; kk++)
                    a[kk] = *(const short8*)(gbt + (m0 + l16) * 96 + kk * 32 + quad * 8);
                f32x4 acc[6];
#pragma unroll
                for (int nt = 0; nt < 6; nt++) acc[nt] = (f32x4){0.f, 0.f, 0.f, 0.f};
#pragma unroll
                for (int nt = 0; nt < 6; nt++) {
#pragma unroll
                    for (int kk = 0; kk < 3; kk++) {
                        short8 bf = *(const short8*)&C1t[(nt * 16 + l16) * GST + kk * 32 + quad * 8];
                        acc[nt] = __builtin_amdgcn_mfma_f32_16x16x32_bf16(a[kk], bf, acc[nt], 0, 0, 0);
                    }
                }
#pragma unroll
                for (int nt = 0; nt < 6; nt++) {
                    int x = nt * 16 + l16;
                    float sx = sxt[x];
#pragma unroll
                    for (int r = 0; r < 4; r++) {
                        int y = m0 + quad * 4 + r;
                        float invn = __builtin_amdgcn_rcpf(sxt[y] * sx);
                        outp[y * 96 + x] = acc[nt][r] * invn;
                    }
                }
            }
            __syncthreads();   // drains stores (vmcnt(0) before barrier)
            if (tid == 0)
                __hip_atomic_fetch_add(&cflag[it * 2 + t / CC], 1u,
                                       __ATOMIC_RELEASE, __HIP_MEMORY_SCOPE_AGENT);
            swLoaded = false;  // C1t overwrote sW region
            continue;
        }

        // ---- tile role ----
        int bt = t - NCONV;                   // 0..1151
        int b = bt / NT16, tile16 = bt - b * NT16;
        if (!swLoaded) {
            for (int t2 = tid; t2 < 441; t2 += 512) {
                sW[t2] = Ws[t2]; sW[441 + t2] = Wb[t2]; sW[882 + t2] = Mmat[t2];
            }
            swLoaded = true;
            __syncthreads();
        }

        // mask: keep-list (8 waves redundant, identical values)
        const float* bndf = (const float*)bnd;
        const float* tb = bndf + (size_t)bt * 6;
        float tlo0 = tb[0], thi0 = tb[1], tlo1 = tb[2], thi1 = tb[3], tlo2 = tb[4], thi2 = tb[5];
        const float* bb = bndf + (size_t)b * NT16 * 6;
        int n = 0;
#pragma unroll
        for (int r = 0; r < 5; r++) {
            int jb = r * 64 + lane;
            bool keep = false;
            if (jb < NJB) {
                const float* a0 = bb + (size_t)(2 * jb) * 6;
                float s = 0.f;
#pragma unroll
                for (int f = 0; f < 3; f++) {
                    float jlo = fminf(a0[2 * f], a0[6 + 2 * f]);
                    float jhi = fmaxf(a0[2 * f + 1], a0[6 + 2 * f + 1]);
                    float lo = (f == 0) ? tlo0 : (f == 1) ? tlo1 : tlo2;
                    float hi = (f == 0) ? thi0 : (f == 1) ? thi1 : thi2;
                    float gap = fmaxf(0.f, fmaxf(lo - jhi, jlo - hi));
                    s = fmaf(gap, gap, s);
                }
                keep = (s <= PRUNE_T);
            }
            unsigned long long m = __ballot(keep);
            if (keep) {
                int pre = __popcll(m & ((1ull << lane) - 1ull));
                jl[n + pre] = (unsigned short)jb;
            }
            n += __popcll(m);
        }
        __syncthreads();

        // bilateral: 8 waves split keep-list stride-8 (dot-product form)
        int i = tile16 * 16 + l16;
        const float* fb = fjs + (size_t)b * 6 * NN;
        float fi0 = fb[0 * NN + i], fi1 = fb[1 * NN + i], fi2 = fb[2 * NN + i];
        float fi3 = fb[3 * NN + i], fi4 = fb[4 * NN + i];
        float ai = -(fi0*fi0 + fi1*fi1 + fi2*fi2 + fi3*fi3 + fi4*fi4);
        float g0 = 2.f*fi0, g1 = 2.f*fi1, g2 = 2.f*fi2, g3 = 2.f*fi3, g4 = 2.f*fi4;
        f32x4 acc0 = {0.f, 0.f, 0.f, 0.f};
        f32x4 acc1 = {0.f, 0.f, 0.f, 0.f};
        const unsigned short* smb = smht_r + (size_t)b * 32 * NN;
        int k = w;
        if (k < n) {
            JSet A, B;
            load_jset(A, fb, smb, jl[k], quad, l16);
            while (true) {
                int kn = k + 8;
                load_jset(B, fb, smb, jl[kn < n ? kn : k], quad, l16);
                compute_jset(A, g0, g1, g2, g3, g4, ai, acc0, acc1);
                k = kn;
                if (k >= n) break;
                kn = k + 8;
                load_jset(A, fb, smb, jl[kn < n ? kn : k], quad, l16);
                compute_jset(B, g0, g1, g2, g3, g4, ai, acc0, acc1);
                k = kn;
                if (k >= n) break;
            }
        }
#pragma unroll
        for (int r = 0; r < 4; r++)
            cbuf[w * 384 + (quad * 4 + r) * 24 + l16] = acc0[r];
        if (l16 < 6) {
#pragma unroll
            for (int r = 0; r < 4; r++)
                cbuf[w * 384 + (quad * 4 + r) * 24 + 16 + l16] = acc1[r];
        }
        __syncthreads();

        // pre-wait prep (reads cbuf/LDS only) + flag wait (acquire LATE)
        if (tid < 16) {
            sinvp[tid] = sinv[b * NN + tile16 * 16 + tid];
            float s4 = 0.f;
#pragma unroll
            for (int ww = 0; ww < 8; ww++) s4 += cbuf[ww * 384 + tid * 24 + 21];
            ninvb[tid] = 1.0f / s4;
        }
        if (tid == 0) {
            while (__hip_atomic_load(&cflag[it * 2 + b], __ATOMIC_RELAXED,
                                     __HIP_MEMORY_SCOPE_AGENT) < (unsigned)CC)
                __builtin_amdgcn_s_sleep(2);
            (void)__hip_atomic_load(&cflag[it * 2 + b], __ATOMIC_ACQUIRE,
                                    __HIP_MEMORY_SCOPE_AGENT);
        }
        __syncthreads();

        // blv/spv in registers (cbuf is LDS, unaffected by acquire)
        int rr = 0, cc2 = 0, pp = 0;
        float blv_r = 0.f, spv_r = 0.f;
        if (tid < 16 * CC) {
            rr = tid / CC; cc2 = tid - rr * CC;
            float s4 = 0.f;
#pragma unroll
            for (int ww = 0; ww < 8; ww++) s4 += cbuf[ww * 384 + rr * 24 + cc2];
            blv_r = s4 * ninvb[rr];
            pp = sinvp[rr];
            spv_r = spf[(size_t)(b * CC + cc2) * NN + pp];
        }
        __syncthreads();                        // all cbuf reads complete
        if (tid < 16 * CC) { blvb[tid] = blv_r; spvb[tid] = spv_r; }
        __syncthreads();
        float msg_r = 0.f;
        if (tid < 16 * CC) {
            const float* wr2 = &sW[cc2 * CC];
            const float* br = &sW[441 + cc2 * CC];
#pragma unroll
            for (int c2 = 0; c2 < CC; c2++) msg_r = fmaf(wr2[c2], spvb[rr * CC + c2], msg_r);
#pragma unroll
            for (int c2 = 0; c2 < CC; c2++) msg_r = fmaf(br[c2], blvb[rr * CC + c2], msg_r);
        }
        __syncthreads();
        if (tid < 16 * CC) msgb[tid] = msg_r;
        __syncthreads();
        if (tid < 16 * CC) {
            float a = u[((size_t)b * NN + pp) * CC + cc2];
            const float* mr = &sW[882 + cc2 * CC];
#pragma unroll
            for (int c2 = 0; c2 < CC; c2++) a = fmaf(-mr[c2], msgb[rr * CC + c2], a);
            if (wr) qvb[tid] = a;
            else qout[((size_t)b * NN + pp) * CC + cc2] = a;
        }
        if (wr) {
            __syncthreads();
            if (tid < 16) {
                int r = tid;
                float m = -1e30f;
#pragma unroll
                for (int c = 0; c < CC; c++) m = fmaxf(m, qvb[r * CC + c]);
                float ssum = 0.f;
                float ev[CC];
#pragma unroll
                for (int c = 0; c < CC; c++) { ev[c] = __expf(qvb[r * CC + c] - m); ssum += ev[c]; }
                float inv = 1.0f / ssum;
                int p = sinvp[r];
                int s = tile16 * 16 + r;
#pragma unroll
                for (int c = 0; c < CC; c++) {
                    unsigned short h = bf16_1(ev[c] * inv);
                    smpb[(size_t)(b * CC + c) * NN + p] = h;
                    smht_w[(size_t)(b * 32 + c) * NN + s] = h;
                }
            }
        }
    }
}

extern "C" void kernel_launch(void* const* d_in, const int* in_sizes, int n_in,
                              void* d_out, int out_size, void* d_ws, size_t ws_size,
                              hipStream_t stream)
{
    const float* unary = (const float*)d_in[0];  // [B,H,W,C]
    const float* rgb   = (const float*)d_in[1];  // [B,H,W,3]
    const float* Ws    = (const float*)d_in[2];
    const float* Wb    = (const float*)d_in[3];
    const float* M     = (const float*)d_in[4];
    float* out = (float*)d_out;                  // [B,N,C]

    float* SXT  = (float*)d_ws;                            // 96
    float* FJS  = SXT + 96;                                // B*6*N (5 feats + norm)
    float* SPF  = FJS + (size_t)BB * 6 * NN;               // B*21*N
    unsigned* BND = (unsigned*)(SPF + (size_t)BB * CC * NN);   // B*576*6
    unsigned* GHA = BND + (size_t)BB * NT16 * 6;           // B*4096 (poison-based)
    unsigned* GHB = GHA + BB * 4096;                       // B*4096 (poison-based)
    unsigned* CFLAG = GHB + BB * 4096;                     // 24 (flags + tickets)
    unsigned* TK = CFLAG + 16;                             // tickets tk[it]
    unsigned* SENT = CFLAG + 24;                           // 1 (NEVER written)
    int*   SINV = (int*)(SENT + 1);                        // B*N
    unsigned short* SMHT0 = (unsigned short*)(SINV + BB * NN); // B*32*N
    unsigned short* SMHT1 = SMHT0 + (size_t)BB * 32 * NN;  // B*32*N
    unsigned short* SMPB  = SMHT1 + (size_t)BB * 32 * NN;  // B*21*N
    unsigned short* GBT   = SMPB + (size_t)BB * CC * NN;   // 96*96

    histprep_kernel<<<104, 256, 0, stream>>>(rgb, GHA, GHB, SXT, GBT, SMHT0, SMHT1,
                                             BND, CFLAG);
    scanscatter_kernel<<<BB * 36, 256, 0, stream>>>(rgb, GHA, GHB, SENT, SINV,
                                                    FJS, BND, unary, SMPB, SMHT0);
    for (int it = 0; it < 5; ++it) {
        unsigned short* SR = (it & 1) ? SMHT1 : SMHT0;
        unsigned short* SW = (it & 1) ? SMHT0 : SMHT1;
        crf_iter_kernel<<<NGRID, 512, 0, stream>>>(
            SMPB, GBT, SXT, SPF, SR, SW, FJS, BND, SINV, unary,
            Ws, Wb, M, out, CFLAG, TK, it, (it < 4) ? 1 : 0);
    }
}

// Round 12
// 274.534 us; speedup vs baseline: 2.3166x; 1.7557x over previous
//
#include <hip/hip_runtime.h>

#define HH 96
#define WW 96
#define CC 21
#define BB 2
#define NN (HH*WW)          // 9216
#define NT16 (NN/16)        // 576 sorted 16-tiles per batch
#define NJB  (NN/32)        // 288 j-blocks per batch
#define NCONV (BB*CC)       // 42 conv blocks
#define NBILB (BB*NT16)     // 1152 bilateral blocks (one tile per block)
#define PRUNE_T 20.0f       // exp2-domain skip threshold (mass <= N*2^-20)
#define GST 104             // LDS row stride for 96-wide bf16 rows

// feature pre-scale folds 1/2 and log2(e): k = exp2(-sum(diff^2))
#define KSA2 (0.84932184f / 160.0f)   // bilateral spatial
#define KSB2 (0.84932184f / 3.0f)     // bilateral color
#define GL2  (1.44269504f / 18.0f)    // spatial kernel exp(-d^2/18) in exp2 units

typedef __attribute__((ext_vector_type(4))) float f32x4;
typedef __attribute__((ext_vector_type(8))) short short8;
typedef __attribute__((ext_vector_type(4))) int int4v;

static __device__ inline unsigned pk_bf16(float a, float b) {
    unsigned ua = __builtin_bit_cast(unsigned, a);
    unsigned ub = __builtin_bit_cast(unsigned, b);
    ua += 0x7FFF + ((ua >> 16) & 1);
    ub += 0x7FFF + ((ub >> 16) & 1);
    return (ua >> 16) | (ub & 0xFFFF0000u);
}
static __device__ inline unsigned short bf16_1(float a) {
    unsigned ua = __builtin_bit_cast(unsigned, a);
    ua += 0x7FFF + ((ua >> 16) & 1);
    return (unsigned short)(ua >> 16);
}

// ===== D1: dual hist (poison-based) + tables + smht const rows + BND init ==
__global__ __launch_bounds__(256) void histprep_kernel(
    const float* __restrict__ rgb, unsigned* __restrict__ gha,
    unsigned* __restrict__ ghb, float* __restrict__ sxt,
    unsigned short* __restrict__ gbt, unsigned short* __restrict__ smht,
    unsigned* __restrict__ bnd)
{
    int tid = threadIdx.x;
    int gid = blockIdx.x * 256 + tid;
    if (gid < BB * NN) {
        int b = gid / NN;
        const float* rp = rgb + (size_t)gid * 3;
        int cr = min(15, (int)rp[0] >> 4);
        int cg = min(15, (int)rp[1] >> 4);
        int cb = min(15, (int)rp[2] >> 4);
        int cell = b * 4096 + ((cr << 8) | (cg << 4) | cb);
        atomicAdd(&gha[cell], 1u);
        atomicAdd(&ghb[cell], 1u);
    }
    unsigned* smd = (unsigned*)smht;
    for (int o = gid; o < BB * 11 * (NN / 2); o += 104 * 256) {
        int b = o / (11 * (NN / 2));
        int rem = o - b * 11 * (NN / 2);
        int rr = rem / (NN / 2), col = rem - rr * (NN / 2);
        smd[(size_t)(b * 32 + 21 + rr) * (NN / 2) + col] = (rr == 0) ? 0x3F803F80u : 0u;
    }
    if (gid < BB * NT16 * 3) {
        int t2 = gid / 3, f = gid - t2 * 3;
        bnd[t2 * 6 + 2 * f]     = 0x7F7FFFFFu;   // lo = +FLT_MAX bits (poison-proof)
        bnd[t2 * 6 + 2 * f + 1] = 0u;            // hi = 0 (features >= 0)
    }
    if (blockIdx.x == 0) {
        __shared__ float gt[96];
        if (tid < 96) gt[tid] = __builtin_amdgcn_exp2f(-(float)(tid * tid) * GL2);
        __syncthreads();
        if (tid < 96) {
            float s = 0.f;
            for (int v = 0; v < 96; v++) s += gt[abs(tid - v)];
            sxt[tid] = s;
            for (int v = 0; v < 96; v++) gbt[tid * 96 + v] = bf16_1(gt[abs(tid - v)]);
        }
    }
}

// ===== D2: fused scan + scatter + bbox + sinv + iteration-0 softmax ========
__global__ __launch_bounds__(256) void scanscatter_kernel(
    const float* __restrict__ rgb, const unsigned* __restrict__ gha,
    unsigned* __restrict__ ghb, const unsigned* __restrict__ sent,
    int* __restrict__ spos, int* __restrict__ sinv,
    float* __restrict__ fjs, unsigned* __restrict__ bnd,
    const float* __restrict__ q, unsigned short* __restrict__ smpb,
    unsigned short* __restrict__ smht)
{
    __shared__ int sOff[4096];
    __shared__ int ps[256];
    unsigned sv = sent[0];
    int t = threadIdx.x;
    int blk = blockIdx.x;
    int b = blk / (36);                       // 36 blocks per batch
    int base = b * 4096 + t * 16;
    int loc[16], s = 0;
#pragma unroll
    for (int k = 0; k < 16; k++) { loc[k] = (int)(gha[base + k] - sv); s += loc[k]; }
    ps[t] = s;
    __syncthreads();
    for (int off = 1; off < 256; off <<= 1) {
        int add = (t >= off) ? ps[t - off] : 0;
        __syncthreads();
        ps[t] += add;
        __syncthreads();
    }
    int run = ps[t] - s;
#pragma unroll
    for (int k = 0; k < 16; k++) { sOff[t * 16 + k] = run; run += loc[k]; }
    __syncthreads();
    int idx = blk * 256 + t;                  // global pixel, == b*NN + p
    int p = idx - b * NN;
    const float* rp = rgb + (size_t)idx * 3;
    float r = rp[0], g = rp[1], bl = rp[2];
    int cr = min(15, (int)r >> 4);
    int cg = min(15, (int)g >> 4);
    int cb = min(15, (int)bl >> 4);
    int cell = (cr << 8) | (cg << 4) | cb;
    unsigned old = atomicSub(&ghb[b * 4096 + cell], 1u);
    int pos = sOff[cell] + (int)(old - sv) - 1;
    spos[idx] = pos;
    sinv[b * NN + pos] = p;                   // inverse permutation (sorted -> pixel)
    int y = p / WW, x = p - y * WW;
    float fr = r * KSB2, fg = g * KSB2, fb2 = bl * KSB2;
    float* fb = fjs + (size_t)b * 5 * NN;
    fb[0 * NN + pos] = fr;
    fb[1 * NN + pos] = fg;
    fb[2 * NN + pos] = fb2;
    fb[3 * NN + pos] = (float)y * KSA2;
    fb[4 * NN + pos] = (float)x * KSA2;
    unsigned* bq = bnd + (size_t)(b * NT16 + (pos >> 4)) * 6;
    atomicMin(&bq[0], __float_as_uint(fr));  atomicMax(&bq[1], __float_as_uint(fr));
    atomicMin(&bq[2], __float_as_uint(fg));  atomicMax(&bq[3], __float_as_uint(fg));
    atomicMin(&bq[4], __float_as_uint(fb2)); atomicMax(&bq[5], __float_as_uint(fb2));
    const float* qp = q + (size_t)idx * CC;
    float v[CC], mx = -1e30f;
#pragma unroll
    for (int c = 0; c < CC; c++) { v[c] = qp[c]; mx = fmaxf(mx, v[c]); }
    float ssum = 0.f;
#pragma unroll
    for (int c = 0; c < CC; c++) { v[c] = __expf(v[c] - mx); ssum += v[c]; }
    float inv = 1.0f / ssum;
#pragma unroll
    for (int c = 0; c < CC; c++) {
        unsigned short h = bf16_1(v[c] * inv);
        smpb[(size_t)(b * CC + c) * NN + p] = h;
        smht[(size_t)(b * 32 + c) * NN + pos] = h;
    }
}

// ---------------- bilateral helpers (depth-2 pipelined j-set) --------------
struct JSet { float vf[5][8]; short8 sb0, sb1; };

static __device__ __forceinline__ void load_jset(
    JSet& s, const float* __restrict__ fb, const unsigned short* __restrict__ smb,
    int jb, int quad, int l16)
{
    int coff = jb * 32 + quad * 8;
#pragma unroll
    for (int f = 0; f < 5; f++) {
        const float4* pf = (const float4*)(fb + (size_t)f * NN + coff);
        float4 lo = pf[0], hi = pf[1];
        s.vf[f][0] = lo.x; s.vf[f][1] = lo.y; s.vf[f][2] = lo.z; s.vf[f][3] = lo.w;
        s.vf[f][4] = hi.x; s.vf[f][5] = hi.y; s.vf[f][6] = hi.z; s.vf[f][7] = hi.w;
    }
    s.sb0 = *(const short8*)(smb + (size_t)l16 * NN + coff);
    s.sb1 = *(const short8*)(smb + (size_t)(16 + l16) * NN + coff);
}

static __device__ __forceinline__ void compute_jset(
    const JSet& s, float fi0, float fi1, float fi2, float fi3, float fi4,
    f32x4& acc0, f32x4& acc1)
{
    float kf[8];
#pragma unroll
    for (int e = 0; e < 8; e++) {
        float d0 = s.vf[0][e] - fi0;
        float d1 = s.vf[1][e] - fi1;
        float d2 = s.vf[2][e] - fi2;
        float d3 = s.vf[3][e] - fi3;
        float d4 = s.vf[4][e] - fi4;
        float sm = d0 * d0;
        sm = fmaf(d1, d1, sm);
        sm = fmaf(d2, d2, sm);
        sm = fmaf(d3, d3, sm);
        sm = fmaf(d4, d4, sm);
        kf[e] = __builtin_amdgcn_exp2f(-sm);
    }
    int4v ap = { (int)pk_bf16(kf[0], kf[1]), (int)pk_bf16(kf[2], kf[3]),
                 (int)pk_bf16(kf[4], kf[5]), (int)pk_bf16(kf[6], kf[7]) };
    short8 afrag = __builtin_bit_cast(short8, ap);
    acc0 = __builtin_amdgcn_mfma_f32_16x16x32_bf16(afrag, s.sb0, acc0, 0, 0, 0);
    acc1 = __builtin_amdgcn_mfma_f32_16x16x32_bf16(afrag, s.sb1, acc1, 0, 0, 0);
}

// ===== K2: conv + bilateral ==================================================
// Blocks 0..41: separable spatial conv per (b,c) plane (2x MFMA passes).
// Blocks 42..1193: ONE sorted 16-tile per BLOCK; 4 waves split the keep-list
// stride-4, partial sums combined via LDS (no global atomics). Results are
// written pixel-ordered via sinv so the update kernel reads them coalesced.
__global__ __launch_bounds__(256) void conv_bil_kernel(
    const unsigned short* __restrict__ smpb, const unsigned short* __restrict__ gbt,
    const float* __restrict__ sxt, float* __restrict__ spf,
    const unsigned short* __restrict__ smht_c, const float* __restrict__ fjs,
    const unsigned* __restrict__ bnd, const int* __restrict__ sinv,
    float* __restrict__ pix)
{
    __shared__ __align__(16) char sh[19968];   // conv C1t | bil {jl, combine buf}
    int tid = threadIdx.x;
    int lane = tid & 63, w = tid >> 6;
    int quad = lane >> 4, l16 = lane & 15;
    int bid = blockIdx.x;

    if (bid < NCONV) {
        unsigned short* C1t = (unsigned short*)sh;
        const unsigned short* plane = smpb + (size_t)bid * NN;
        for (int mt = w; mt < 6; mt += 4) {
            int m0 = mt * 16;
            short8 a[3];
#pragma unroll
            for (int kk = 0; kk < 3; kk++)
                a[kk] = *(const short8*)(plane + (size_t)(m0 + l16) * 96 + kk * 32 + quad * 8);
            f32x4 acc[6];
#pragma unroll
            for (int nt = 0; nt < 6; nt++) acc[nt] = (f32x4){0.f, 0.f, 0.f, 0.f};
#pragma unroll
            for (int nt = 0; nt < 6; nt++) {
#pragma unroll
                for (int kk = 0; kk < 3; kk++) {
                    short8 bf = *(const short8*)(gbt + (nt * 16 + l16) * 96 + kk * 32 + quad * 8);
                    acc[nt] = __builtin_amdgcn_mfma_f32_16x16x32_bf16(a[kk], bf, acc[nt], 0, 0, 0);
                }
            }
#pragma unroll
            for (int nt = 0; nt < 6; nt++) {
                unsigned* dst = (unsigned*)&C1t[(nt * 16 + l16) * GST + m0 + quad * 4];
                dst[0] = pk_bf16(acc[nt][0], acc[nt][1]);
                dst[1] = pk_bf16(acc[nt][2], acc[nt][3]);
            }
        }
        __syncthreads();
        float* outp = spf + (size_t)bid * NN;
        for (int mt = w; mt < 6; mt += 4) {
            int m0 = mt * 16;
            short8 a[3];
#pragma unroll
            for (int kk = 0; kk < 3; kk++)
                a[kk] = *(const short8*)(gbt + (m0 + l16) * 96 + kk * 32 + quad * 8);
            f32x4 acc[6];
#pragma unroll
            for (int nt = 0; nt < 6; nt++) acc[nt] = (f32x4){0.f, 0.f, 0.f, 0.f};
#pragma unroll
            for (int nt = 0; nt < 6; nt++) {
#pragma unroll
                for (int kk = 0; kk < 3; kk++) {
                    short8 bf = *(const short8*)&C1t[(nt * 16 + l16) * GST + kk * 32 + quad * 8];
                    acc[nt] = __builtin_amdgcn_mfma_f32_16x16x32_bf16(a[kk], bf, acc[nt], 0, 0, 0);
                }
            }
#pragma unroll
            for (int nt = 0; nt < 6; nt++) {
                int x = nt * 16 + l16;
                float sx = sxt[x];
#pragma unroll
                for (int r = 0; r < 4; r++) {
                    int y = m0 + quad * 4 + r;
                    float invn = __builtin_amdgcn_rcpf(sxt[y] * sx);
                    outp[y * 96 + x] = acc[nt][r] * invn;
                }
            }
        }
        return;
    }

    // ---- bilateral: block owns tile bt; 4 waves split keep-list stride-4 ----
    int bt = bid - NCONV;                     // 0..1151
    int b = bt / NT16, tile16 = bt - b * NT16;
    unsigned short* jl = (unsigned short*)sh;         // 288 * 2B
    float* cbuf = (float*)(sh + 1024);                // 4 * 16 * 24 * 4B = 6144 B
    const float* bndf = (const float*)bnd;
    const float* tb = bndf + (size_t)bt * 6;
    float tlo0 = tb[0], thi0 = tb[1], tlo1 = tb[2], thi1 = tb[3], tlo2 = tb[4], thi2 = tb[5];
    const float* bb = bndf + (size_t)b * NT16 * 6;
    int n = 0;
#pragma unroll
    for (int r = 0; r < 5; r++) {
        int jb = r * 64 + lane;
        bool keep = false;
        if (jb < NJB) {
            const float* a0 = bb + (size_t)(2 * jb) * 6;
            float s = 0.f;
#pragma unroll
            for (int f = 0; f < 3; f++) {
                float jlo = fminf(a0[2 * f], a0[6 + 2 * f]);
                float jhi = fmaxf(a0[2 * f + 1], a0[6 + 2 * f + 1]);
                float lo = (f == 0) ? tlo0 : (f == 1) ? tlo1 : tlo2;
                float hi = (f == 0) ? thi0 : (f == 1) ? thi1 : thi2;
                float gap = fmaxf(0.f, fmaxf(lo - jhi, jlo - hi));
                s = fmaf(gap, gap, s);
            }
            keep = (s <= PRUNE_T);
        }
        unsigned long long m = __ballot(keep);
        if (keep) {
            int pre = __popcll(m & ((1ull << lane) - 1ull));
            jl[n + pre] = (unsigned short)jb;   // all 4 waves write identical values
        }
        n += __popcll(m);
    }
    __syncthreads();

    int i = tile16 * 16 + l16;
    const float* fb = fjs + (size_t)b * 5 * NN;
    float fi0 = fb[0 * NN + i], fi1 = fb[1 * NN + i], fi2 = fb[2 * NN + i];
    float fi3 = fb[3 * NN + i], fi4 = fb[4 * NN + i];
    f32x4 acc0 = {0.f, 0.f, 0.f, 0.f};
    f32x4 acc1 = {0.f, 0.f, 0.f, 0.f};
    const unsigned short* smb = smht_c + (size_t)b * 32 * NN;
    int k = w;                                // wave handles jl[w], jl[w+4], ...
    if (k < n) {
        JSet A, B;
        load_jset(A, fb, smb, jl[k], quad, l16);
        while (true) {
            int kn = k + 4;
            load_jset(B, fb, smb, jl[kn < n ? kn : k], quad, l16);
            compute_jset(A, fi0, fi1, fi2, fi3, fi4, acc0, acc1);
            k = kn;
            if (k >= n) break;
            kn = k + 4;
            load_jset(A, fb, smb, jl[kn < n ? kn : k], quad, l16);
            compute_jset(B, fi0, fi1, fi2, fi3, fi4, acc0, acc1);
            k = kn;
            if (k >= n) break;
        }
    }
    // combine 4 waves' partials via LDS, then store pixel-ordered (no atomics)
#pragma unroll
    for (int r = 0; r < 4; r++)
        cbuf[w * 384 + (quad * 4 + r) * 24 + l16] = acc0[r];
    if (l16 < 6) {
#pragma unroll
        for (int r = 0; r < 4; r++)
            cbuf[w * 384 + (quad * 4 + r) * 24 + 16 + l16] = acc1[r];
    }
    __syncthreads();
    const int* sv = sinv + b * NN;
    for (int e = tid; e < 16 * 22; e += 256) {
        int row = e / 22, col = e - row * 22;
        float s2 = cbuf[row * 24 + col] + cbuf[384 + row * 24 + col]
                 + cbuf[768 + row * 24 + col] + cbuf[1152 + row * 24 + col];
        int p = sv[tile16 * 16 + row];
        pix[((size_t)b * NN + p) * 24 + col] = s2;
    }
}

// ------- K3: norm + messages + update + next-iter softmax (144x128) --------
__global__ __launch_bounds__(128) void update_fused_kernel(
    const float* __restrict__ u, const float* __restrict__ spf,
    const float* __restrict__ pix, const int* __restrict__ spos,
    const float* __restrict__ Ws, const float* __restrict__ Wb,
    const float* __restrict__ M, float* __restrict__ qout,
    unsigned short* __restrict__ smpb, unsigned short* __restrict__ smht, int wr)
{
    __shared__ float sW[3 * 441];
    int idx = blockIdx.x * 128 + threadIdx.x;
    int b = idx / NN, p = idx - b * NN;
    int s = spos[idx];
    const float* pp = pix + (size_t)idx * 24;   // pixel-ordered, coalesced
    float blv[22];
#pragma unroll
    for (int c = 0; c < 22; c++) blv[c] = pp[c];
    float spv[CC];
#pragma unroll
    for (int c = 0; c < CC; c++) spv[c] = spf[(size_t)(b * CC + c) * NN + p];
    const float* up = u + (size_t)idx * CC;
    float uv[CC];
#pragma unroll
    for (int c = 0; c < CC; c++) uv[c] = up[c];
    for (int t = threadIdx.x; t < 441; t += 128) {
        sW[t] = Ws[t]; sW[441 + t] = Wb[t]; sW[882 + t] = M[t];
    }
    __syncthreads();
    float ninv = 1.0f / blv[21];
#pragma unroll
    for (int c = 0; c < CC; c++) blv[c] *= ninv;
    float msg[CC];
#pragma unroll
    for (int c = 0; c < CC; c++) {
        float a = 0.f;
        const float* wr2 = &sW[c * CC];
        const float* br = &sW[441 + c * CC];
#pragma unroll
        for (int c2 = 0; c2 < CC; c2++) a = fmaf(wr2[c2], spv[c2], a);
#pragma unroll
        for (int c2 = 0; c2 < CC; c2++) a = fmaf(br[c2], blv[c2], a);
        msg[c] = a;
    }
    float qv[CC];
#pragma unroll
    for (int c = 0; c < CC; c++) {
        float a = uv[c];
        const float* mr = &sW[882 + c * CC];
#pragma unroll
        for (int c2 = 0; c2 < CC; c2++) a = fmaf(-mr[c2], msg[c2], a);
        qv[c] = a;
    }
    if (wr) {
        float m = -1e30f;
#pragma unroll
        for (int c = 0; c < CC; c++) m = fmaxf(m, qv[c]);
        float ssum = 0.f;
        float ev[CC];
#pragma unroll
        for (int c = 0; c < CC; c++) { ev[c] = __expf(qv[c] - m); ssum += ev[c]; }
        float inv = 1.0f / ssum;
#pragma unroll
        for (int c = 0; c < CC; c++) {
            unsigned short h = bf16_1(ev[c] * inv);
            smpb[(size_t)(b * CC + c) * NN + p] = h;
            smht[(size_t)(b * 32 + c) * NN + s] = h;
        }
    } else {
        float* qp = qout + (size_t)idx * CC;
#pragma unroll
        for (int c = 0; c < CC; c++) qp[c] = qv[c];
    }
}

extern "C" void kernel_launch(void* const* d_in, const int* in_sizes, int n_in,
                              void* d_out, int out_size, void* d_ws, size_t ws_size,
                              hipStream_t stream)
{
    const float* unary = (const float*)d_in[0];  // [B,H,W,C]
    const float* rgb   = (const float*)d_in[1];  // [B,H,W,3]
    const float* Ws    = (const float*)d_in[2];
    const float* Wb    = (const float*)d_in[3];
    const float* M     = (const float*)d_in[4];
    float* out = (float*)d_out;                  // [B,N,C]

    float* SXT  = (float*)d_ws;                            // 96
    float* FJS  = SXT + 96;                                // B*5*N
    float* SPF  = FJS + (size_t)BB * 5 * NN;               // B*21*N
    float* PIX  = SPF + (size_t)BB * CC * NN;              // B*N*24 (pixel-ordered)
    unsigned* BND = (unsigned*)(PIX + (size_t)BB * NN * 24);   // B*576*6
    int*   SPOS = (int*)(BND + (size_t)BB * NT16 * 6);     // B*N
    unsigned* GHA = (unsigned*)(SPOS + BB * NN);           // B*4096 (poison-based)
    unsigned* GHB = GHA + BB * 4096;                       // B*4096 (poison-based)
    int*   CNT  = (int*)(GHB + BB * 4096);                 // B*576 (unused)
    unsigned* WLC = (unsigned*)(CNT + BB * NT16);          // 1 (unused)
    unsigned* SENT = WLC + 1;                              // 1 (NEVER written)
    int*   SINV = (int*)(SENT + 1);                        // B*N
    unsigned short* JL = (unsigned short*)(SINV + BB * NT16 * 36);  // unused
    unsigned short* SMHT = JL + (size_t)BB * NT16 * NJB;   // B*32*N
    unsigned short* SMPB = SMHT + (size_t)BB * 32 * NN;    // B*21*N
    unsigned short* GBT  = SMPB + (size_t)BB * CC * NN;    // 96*96

    histprep_kernel<<<104, 256, 0, stream>>>(rgb, GHA, GHB, SXT, GBT, SMHT, BND);
    scanscatter_kernel<<<BB * 36, 256, 0, stream>>>(rgb, GHA, GHB, SENT, SPOS, SINV,
                                                    FJS, BND, unary, SMPB, SMHT);
    for (int it = 0; it < 5; ++it) {
        conv_bil_kernel<<<NCONV + NBILB, 256, 0, stream>>>(
            SMPB, GBT, SXT, SPF, SMHT, FJS, BND, SINV, PIX);
        update_fused_kernel<<<(BB * NN + 127) / 128, 128, 0, stream>>>(
            unary, SPF, PIX, SPOS, Ws, Wb, M, out, SMPB, SMHT, (it < 4) ? 1 : 0);
    }
}